// Round 5
// baseline (602.759 us; speedup 1.0000x reference)
//
#include <hip/hip_runtime.h>
#include <stdint.h>

#define NTHREADS 256
#define KTOP 50
#define CAP 1024
#define CAPREF 768
#define EPSV 1e-8f
#define GV 4

typedef unsigned long long u64;

// ---- block-wide float max (s_f: 8 floats scratch) ----
__device__ __forceinline__ float block_max(float v, float* s_f, int tid) {
    for (int off = 32; off; off >>= 1) v = fmaxf(v, __shfl_down(v, off));
    if ((tid & 63) == 0) s_f[tid >> 6] = v;
    __syncthreads();
    if (tid == 0) {
        float m = s_f[0];
        for (int w = 1; w < NTHREADS / 64; ++w) m = fmaxf(m, s_f[w]);
        s_f[4] = m;
    }
    __syncthreads();
    float r = s_f[4];
    __syncthreads();
    return r;
}

// ---- cold path: per-element direct collect (validated) ----
__device__ int collect_direct(const float* __restrict__ row, int V, float t,
                              u64* cand, uint32_t* s_cnt, int tid) {
    if (tid == 0) *s_cnt = 0;
    __syncthreads();
    auto pushc = [&](float v, int idx) {
        if (v >= t) {
            uint32_t pos = atomicAdd(s_cnt, 1u);
            if (pos < CAP)
                cand[pos] = (((u64)__float_as_uint(v)) << 16) |
                            (u64)(0xFFFFu - (uint32_t)idx);
        }
    };
    int mis = (int)(((uintptr_t)row >> 2) & 3);
    int head = (4 - mis) & 3; if (head > V) head = V;
    if (tid < head) pushc(row[tid], tid);
    int nvec = (V - head) >> 2;
    const float4* vr = reinterpret_cast<const float4*>(row + head);
    for (int i = tid; i < nvec; i += NTHREADS) {
        float4 v = vr[i];
        int b = head + (i << 2);
        pushc(v.x, b); pushc(v.y, b + 1); pushc(v.z, b + 2); pushc(v.w, b + 3);
    }
    for (int i = head + (nvec << 2) + tid; i < V; i += NTHREADS)
        pushc(row[i], i);
    __syncthreads();
    int n = (int)*s_cnt;
    __syncthreads();
    return n;
}

// ---- hot path: 2-deep pipelined 4x-float4 group-test + ref expansion ----
// Returns candidate count, or -1 on ref overflow (caller falls back).
__device__ int collect_fast(const float* __restrict__ row, int V, float t,
                            u64* cand, uint32_t* refs,
                            uint32_t* s_cnt, uint32_t* s_ref, int tid) {
    if (tid == 0) { *s_cnt = 0; *s_ref = 0; }
    __syncthreads();
    auto pushc = [&](float v, int idx) {
        if (v >= t) {
            uint32_t pos = atomicAdd(s_cnt, 1u);
            if (pos < CAP)
                cand[pos] = (((u64)__float_as_uint(v)) << 16) |
                            (u64)(0xFFFFu - (uint32_t)idx);
        }
    };
    int mis = (int)(((uintptr_t)row >> 2) & 3);
    int head = (4 - mis) & 3; if (head > V) head = V;
    if (tid < head) pushc(row[tid], tid);
    int nvec = (V - head) >> 2;
    const float4* vr = reinterpret_cast<const float4*>(row + head);

    const int per = GV * NTHREADS;
    int ngrp = nvec / per;

    float4 A[GV], B[GV];
    auto loadg = [&](float4* buf, int g) {
        int o = g * per + tid;
        #pragma unroll
        for (int j = 0; j < GV; ++j) buf[j] = vr[o + j * NTHREADS];
    };
    auto procg = [&](float4* buf, int g) {
        float m0 = fmaxf(fmaxf(buf[0].x, buf[0].y), fmaxf(buf[0].z, buf[0].w));
        float m1 = fmaxf(fmaxf(buf[1].x, buf[1].y), fmaxf(buf[1].z, buf[1].w));
        float m2 = fmaxf(fmaxf(buf[2].x, buf[2].y), fmaxf(buf[2].z, buf[2].w));
        float m3 = fmaxf(fmaxf(buf[3].x, buf[3].y), fmaxf(buf[3].z, buf[3].w));
        float mx = fmaxf(fmaxf(m0, m1), fmaxf(m2, m3));
        if (mx >= t) {
            uint32_t rp = atomicAdd(s_ref, 1u);
            if (rp < CAPREF) refs[rp] = (uint32_t)(g * per + tid);
        }
    };

    if (ngrp > 0) loadg(A, 0);
    int g = 0;
    for (; g + 2 <= ngrp; g += 2) {
        loadg(B, g + 1);
        asm volatile("" ::: "memory");   // keep B's loads issued before A's use
        procg(A, g);
        if (g + 2 < ngrp) loadg(A, g + 2);
        asm volatile("" ::: "memory");
        procg(B, g + 1);
    }
    if (g < ngrp) procg(A, g);

    // remainder float4s + scalar tail: direct per-element push
    for (int i = ngrp * per + tid; i < nvec; i += NTHREADS) {
        float4 v = vr[i];
        int b = head + (i << 2);
        pushc(v.x, b); pushc(v.y, b + 1); pushc(v.z, b + 2); pushc(v.w, b + 3);
    }
    for (int i = head + (nvec << 2) + tid; i < V; i += NTHREADS)
        pushc(row[i], i);
    __syncthreads();
    uint32_t nref = *s_ref;
    if (nref > CAPREF) { __syncthreads(); return -1; }
    // expand refs: re-read hit groups (L2-warm) and push per-element
    int units = (int)nref * GV;
    for (int u = tid; u < units; u += NTHREADS) {
        int f4 = (int)refs[u >> 2] + (u & 3) * NTHREADS;
        float4 v = vr[f4];
        int b = head + (f4 << 2);
        pushc(v.x, b); pushc(v.y, b + 1); pushc(v.z, b + 2); pushc(v.w, b + 3);
    }
    __syncthreads();
    int n = (int)*s_cnt;
    __syncthreads();
    return n;
}

// ---- barrier-light exact top-K: per-wave extract in registers, wave0 merge
__device__ void find_topk(const u64* cand, int nc, uint16_t* top,
                          u64* s_merge, int tid) {
    int lane = tid & 63, w = tid >> 6;
    u64 r0 = 0, r1 = 0, r2 = 0, r3 = 0;
    int j0 = (w << 6) + lane;
    if (j0 < nc)       r0 = cand[j0];
    if (j0 + 256 < nc) r1 = cand[j0 + 256];
    if (j0 + 512 < nc) r2 = cand[j0 + 512];
    if (j0 + 768 < nc) r3 = cand[j0 + 768];
    for (int k = 0; k < KTOP; ++k) {
        u64 a = r0 > r1 ? r0 : r1;
        u64 b = r2 > r3 ? r2 : r3;
        u64 m = a > b ? a : b;
        #pragma unroll
        for (int off = 32; off; off >>= 1) {
            u64 o = __shfl_xor(m, off);
            if (o > m) m = o;
        }
        if (lane == 0) s_merge[w * KTOP + k] = m;
        if (r0 == m) r0 = 0; else if (r1 == m) r1 = 0;
        else if (r2 == m) r2 = 0; else if (r3 == m) r3 = 0;
    }
    __syncthreads();
    if (w == 0) {
        u64 q0 = 0, q1 = 0, q2 = 0, q3 = 0;
        if (lane < 4 * KTOP)       q0 = s_merge[lane];
        if (lane + 64 < 4 * KTOP)  q1 = s_merge[lane + 64];
        if (lane + 128 < 4 * KTOP) q2 = s_merge[lane + 128];
        if (lane + 192 < 4 * KTOP) q3 = s_merge[lane + 192];
        for (int k = 0; k < KTOP; ++k) {
            u64 a = q0 > q1 ? q0 : q1;
            u64 b = q2 > q3 ? q2 : q3;
            u64 m = a > b ? a : b;
            #pragma unroll
            for (int off = 32; off; off >>= 1) {
                u64 o = __shfl_xor(m, off);
                if (o > m) m = o;
            }
            if (lane == 0) top[k] = (uint16_t)(0xFFFFu - (uint32_t)(m & 0xFFFFu));
            if (q0 == m) q0 = 0; else if (q1 == m) q1 = 0;
            else if (q2 == m) q2 = 0; else if (q3 == m) q3 = 0;
        }
    }
    __syncthreads();
}

// ---- shared per-(row,array) top-50 selection body ----
__device__ void select_row(const float* __restrict__ rw, int V,
                           u64* cand, uint32_t* refs, u64* s_merge, float* s_f,
                           uint32_t* s_cnt, uint32_t* s_ref, uint16_t* s_top,
                           int tid) {
    int smp = V < 2048 ? V : 2048;
    float ms = 0.f;
    for (int i = tid; i < smp; i += NTHREADS) ms = fmaxf(ms, rw[i]);
    float Ms = block_max(ms, s_f, tid);

    float eps = fminf(128.f / (float)V + 1.f / (float)smp, 0.5f);
    int nc = collect_fast(rw, V, Ms * (1.f - eps), cand, refs, s_cnt, s_ref, tid);
    if (nc < 0) nc = collect_direct(rw, V, Ms * (1.f - eps), cand, s_cnt, tid);
    for (int a = 0; a < 10 && (nc < KTOP || nc > CAP); ++a) {
        eps = (nc > CAP) ? eps * 0.25f : fminf(eps * 4.f, 1.f);
        nc = collect_direct(rw, V, Ms * (1.f - eps), cand, s_cnt, tid);
    }
    if (nc > CAP) nc = CAP;
    find_topk(cand, nc, s_top, s_merge, tid);
}

// ================= phase 1: one block per (row, array) =================
__global__ __launch_bounds__(NTHREADS)
void topk_phase1(const float* __restrict__ p, const float* __restrict__ q,
                 uint16_t* __restrict__ wtop, int V)
{
    __shared__ u64 cand[CAP];
    __shared__ uint32_t refs[CAPREF];
    __shared__ u64 s_merge[4 * KTOP];
    __shared__ float s_f[8];
    __shared__ uint32_t s_cnt, s_ref;
    __shared__ uint16_t s_top[KTOP];

    int bid = blockIdx.x;
    int row = bid >> 1;
    const float* base = (bid & 1) ? q : p;
    const float* rw = base + (size_t)row * (size_t)V;
    int tid = threadIdx.x;

    select_row(rw, V, cand, refs, s_merge, s_f, &s_cnt, &s_ref, s_top, tid);
    if (tid < KTOP) wtop[(size_t)bid * KTOP + tid] = s_top[tid];
}

// ================= phase 2: one wave per row: union + JSD =================
__global__ __launch_bounds__(64)
void jsd_phase2(const float* __restrict__ p, const float* __restrict__ q,
                const uint16_t* __restrict__ wtop, float* __restrict__ out, int V)
{
    __shared__ uint16_t sP[KTOP];
    __shared__ uint16_t s_union[2 * KTOP];
    __shared__ int s_nu;
    int row = blockIdx.x, lane = threadIdx.x;
    const uint16_t* tp = wtop + (size_t)(2 * row) * KTOP;
    const uint16_t* tq = wtop + (size_t)(2 * row + 1) * KTOP;
    const float* prow = p + (size_t)row * (size_t)V;
    const float* qrow = q + (size_t)row * (size_t)V;

    if (lane < KTOP) { uint16_t v = tp[lane]; sP[lane] = v; s_union[lane] = v; }
    __syncthreads();
    bool fresh = false; uint16_t qi = 0;
    if (lane < KTOP) {
        qi = tq[lane]; fresh = true;
        for (int j = 0; j < KTOP; ++j) if (sP[j] == qi) fresh = false;
    }
    u64 mb = __ballot(fresh);
    int pos = __popcll(mb & ((1ull << lane) - 1ull));
    if (fresh) s_union[KTOP + pos] = qi;
    if (lane == 0) s_nu = KTOP + __popcll(mb);
    __syncthreads();
    int nu = s_nu;

    float pv0 = 0.f, qv0 = 0.f, pv1 = 0.f, qv1 = 0.f;
    if (lane < nu)      { int ui = s_union[lane];      pv0 = prow[ui]; qv0 = qrow[ui]; }
    if (lane + 64 < nu) { int ui = s_union[lane + 64]; pv1 = prow[ui]; qv1 = qrow[ui]; }
    float sp = pv0 + pv1, sq = qv0 + qv1;
    for (int off = 32; off; off >>= 1) { sp += __shfl_down(sp, off); sq += __shfl_down(sq, off); }
    sp = __shfl(sp, 0); sq = __shfl(sq, 0);

    auto term = [&](float pv, float qv) -> float {
        float pn = pv / (sp + EPSV);
        float qn = qv / (sq + EPSV);
        float mn = 0.5f * (pn + qn);
        float ps = pn + EPSV, qs = qn + EPSV, msv = mn + EPSV;
        return 0.5f * (ps * logf(ps / msv) + qs * logf(qs / msv));
    };
    float tsum = 0.f;
    if (lane < nu)      tsum += term(pv0, qv0);
    if (lane + 64 < nu) tsum += term(pv1, qv1);
    for (int off = 32; off; off >>= 1) tsum += __shfl_down(tsum, off);
    if (lane == 0) out[row] = tsum;
}

// ============ fallback: validated single-kernel path (R4) ============
__global__ __launch_bounds__(NTHREADS)
void topk_jsd_kernel(const float* __restrict__ p, const float* __restrict__ q,
                     float* __restrict__ out, int V)
{
    __shared__ u64 cand[CAP];
    __shared__ uint32_t refs[CAPREF];
    __shared__ u64 s_merge[4 * KTOP];
    __shared__ float s_f[8];
    __shared__ uint32_t s_cnt, s_ref;
    __shared__ uint16_t topP[KTOP];
    __shared__ uint16_t topQ[KTOP];
    __shared__ uint16_t s_union[2 * KTOP];
    __shared__ int s_nu;

    const int row = blockIdx.x;
    const int tid = threadIdx.x;
    const float* prow = p + (size_t)row * (size_t)V;
    const float* qrow = q + (size_t)row * (size_t)V;

    select_row(prow, V, cand, refs, s_merge, s_f, &s_cnt, &s_ref, topP, tid);
    select_row(qrow, V, cand, refs, s_merge, s_f, &s_cnt, &s_ref, topQ, tid);

    if (tid < KTOP) s_union[tid] = topP[tid];
    __syncthreads();
    if (tid < 64) {
        bool fresh = false; uint16_t qi = 0;
        if (tid < KTOP) {
            qi = topQ[tid]; fresh = true;
            for (int j = 0; j < KTOP; ++j) if (topP[j] == qi) fresh = false;
        }
        unsigned long long mb = __ballot(fresh);
        int pos = __popcll(mb & ((1ull << tid) - 1ull));
        if (fresh) s_union[KTOP + pos] = qi;
        if (tid == 0) s_nu = KTOP + __popcll(mb);
    }
    __syncthreads();
    int nu = s_nu;

    float pv = 0.f, qv = 0.f;
    if (tid < nu) {
        int ui = s_union[tid];
        pv = prow[ui];
        qv = qrow[ui];
    }
    float sp = pv, sq = qv;
    for (int off = 32; off; off >>= 1) { sp += __shfl_down(sp, off); sq += __shfl_down(sq, off); }
    int wid = tid >> 6;
    if ((tid & 63) == 0) { s_f[wid] = sp; s_f[4 + wid] = sq; }
    __syncthreads();
    if (tid == 0) {
        float a = 0.f, b = 0.f;
        for (int w = 0; w < NTHREADS / 64; ++w) { a += s_f[w]; b += s_f[4 + w]; }
        s_f[0] = a; s_f[4] = b;
    }
    __syncthreads();
    float sump = s_f[0], sumq = s_f[4];
    __syncthreads();

    float term = 0.f;
    if (tid < nu) {
        float pn = pv / (sump + EPSV);
        float qn = qv / (sumq + EPSV);
        float mn = 0.5f * (pn + qn);
        float ps = pn + EPSV, qs = qn + EPSV, ms = mn + EPSV;
        term = 0.5f * (ps * logf(ps / ms) + qs * logf(qs / ms));
    }
    for (int off = 32; off; off >>= 1) term += __shfl_down(term, off);
    if ((tid & 63) == 0) s_f[wid] = term;
    __syncthreads();
    if (tid == 0) {
        float a = 0.f;
        for (int w = 0; w < NTHREADS / 64; ++w) a += s_f[w];
        out[row] = a;
    }
}

extern "C" void kernel_launch(void* const* d_in, const int* in_sizes, int n_in,
                              void* d_out, int out_size, void* d_ws, size_t ws_size,
                              hipStream_t stream) {
    const float* p = (const float*)d_in[0];
    const float* q = (const float*)d_in[1];
    float* out = (float*)d_out;
    if (out_size <= 0) return;
    int N = out_size;            // B*S rows
    int V = in_sizes[0] / N;     // vocab size
    size_t need = (size_t)2 * (size_t)N * KTOP * sizeof(uint16_t);
    if (d_ws && ws_size >= need) {
        topk_phase1<<<dim3(2 * N), dim3(NTHREADS), 0, stream>>>(p, q, (uint16_t*)d_ws, V);
        jsd_phase2<<<dim3(N), dim3(64), 0, stream>>>(p, q, (const uint16_t*)d_ws, out, V);
    } else {
        topk_jsd_kernel<<<dim3(N), dim3(NTHREADS), 0, stream>>>(p, q, out, V);
    }
}

// Round 6
// 476.351 us; speedup vs baseline: 1.2654x; 1.2654x over previous
//
#include <hip/hip_runtime.h>
#include <stdint.h>

#define NTHREADS 256
#define KTOP 50
#define CAP 1024
#define CAPREF 512
#define EPSV 1e-8f

typedef unsigned long long u64;

// counters in s_c[]: 0=cntP 1=cntQ 2=refP 3=refQ
#define C_CNTP 0
#define C_CNTQ 1
#define C_REFP 2
#define C_REFQ 3

// ---- block-wide float max (s_f: 8 floats scratch) ----
__device__ __forceinline__ float block_max(float v, float* s_f, int tid) {
    for (int off = 32; off; off >>= 1) v = fmaxf(v, __shfl_down(v, off));
    if ((tid & 63) == 0) s_f[tid >> 6] = v;
    __syncthreads();
    if (tid == 0) {
        float m = s_f[0];
        for (int w = 1; w < NTHREADS / 64; ++w) m = fmaxf(m, s_f[w]);
        s_f[4] = m;
    }
    __syncthreads();
    float r = s_f[4];
    __syncthreads();
    return r;
}

__device__ __forceinline__ void push_cand(u64* cand, uint32_t* cnt,
                                          float v, int idx, float t) {
    if (v >= t) {
        uint32_t pos = atomicAdd(cnt, 1u);
        if (pos < CAP)
            cand[pos] = (((u64)__float_as_uint(v)) << 16) |
                        (u64)(0xFFFFu - (uint32_t)idx);
    }
}

// ---- cold path: per-element direct collect (validated R2-R5) ----
__device__ int collect_direct(const float* __restrict__ row, int V, float t,
                              u64* cand, uint32_t* s_cnt, int tid) {
    if (tid == 0) *s_cnt = 0;
    __syncthreads();
    int mis = (int)(((uintptr_t)row >> 2) & 3);
    int head = (4 - mis) & 3; if (head > V) head = V;
    if (tid < head) push_cand(cand, s_cnt, row[tid], tid, t);
    int nvec = (V - head) >> 2;
    const float4* vr = reinterpret_cast<const float4*>(row + head);
    for (int i = tid; i < nvec; i += NTHREADS) {
        float4 v = vr[i];
        int b = head + (i << 2);
        push_cand(cand, s_cnt, v.x, b, t);     push_cand(cand, s_cnt, v.y, b + 1, t);
        push_cand(cand, s_cnt, v.z, b + 2, t); push_cand(cand, s_cnt, v.w, b + 3, t);
    }
    for (int i = head + (nvec << 2) + tid; i < V; i += NTHREADS)
        push_cand(cand, s_cnt, row[i], i, t);
    __syncthreads();
    int n = (int)*s_cnt;
    __syncthreads();
    return n;
}

__device__ __forceinline__ float max16(float4 a, float4 b, float4 c, float4 d) {
    float m0 = fmaxf(fmaxf(a.x, a.y), fmaxf(a.z, a.w));
    float m1 = fmaxf(fmaxf(b.x, b.y), fmaxf(b.z, b.w));
    float m2 = fmaxf(fmaxf(c.x, c.y), fmaxf(c.z, c.w));
    float m3 = fmaxf(fmaxf(d.x, d.y), fmaxf(d.z, d.w));
    return fmaxf(fmaxf(m0, m1), fmaxf(m2, m3));
}

// ---- barrier-light exact top-K: per-wave extract in registers, wave0 merge
__device__ void find_topk(const u64* cand, int nc, uint16_t* top,
                          u64* s_merge, int tid) {
    int lane = tid & 63, w = tid >> 6;
    u64 r0 = 0, r1 = 0, r2 = 0, r3 = 0;
    int j0 = (w << 6) + lane;
    if (j0 < nc)       r0 = cand[j0];
    if (j0 + 256 < nc) r1 = cand[j0 + 256];
    if (j0 + 512 < nc) r2 = cand[j0 + 512];
    if (j0 + 768 < nc) r3 = cand[j0 + 768];
    for (int k = 0; k < KTOP; ++k) {
        u64 a = r0 > r1 ? r0 : r1;
        u64 b = r2 > r3 ? r2 : r3;
        u64 m = a > b ? a : b;
        #pragma unroll
        for (int off = 32; off; off >>= 1) {
            u64 o = __shfl_xor(m, off);
            if (o > m) m = o;
        }
        if (lane == 0) s_merge[w * KTOP + k] = m;
        if (r0 == m) r0 = 0; else if (r1 == m) r1 = 0;
        else if (r2 == m) r2 = 0; else if (r3 == m) r3 = 0;
    }
    __syncthreads();
    if (w == 0) {
        u64 q0 = 0, q1 = 0, q2 = 0, q3 = 0;
        if (lane < 4 * KTOP)       q0 = s_merge[lane];
        if (lane + 64 < 4 * KTOP)  q1 = s_merge[lane + 64];
        if (lane + 128 < 4 * KTOP) q2 = s_merge[lane + 128];
        if (lane + 192 < 4 * KTOP) q3 = s_merge[lane + 192];
        for (int k = 0; k < KTOP; ++k) {
            u64 a = q0 > q1 ? q0 : q1;
            u64 b = q2 > q3 ? q2 : q3;
            u64 m = a > b ? a : b;
            #pragma unroll
            for (int off = 32; off; off >>= 1) {
                u64 o = __shfl_xor(m, off);
                if (o > m) m = o;
            }
            if (lane == 0) top[k] = (uint16_t)(0xFFFFu - (uint32_t)(m & 0xFFFFu));
            if (q0 == m) q0 = 0; else if (q1 == m) q1 = 0;
            else if (q2 == m) q2 = 0; else if (q3 == m) q3 = 0;
        }
    }
    __syncthreads();
}

__global__ __launch_bounds__(NTHREADS, 4)   // VGPR cap 128: allow deep load ILP
void topk_jsd_kernel(const float* __restrict__ p, const float* __restrict__ q,
                     float* __restrict__ out, int V)
{
    __shared__ u64 candP[CAP];
    __shared__ u64 candQ[CAP];
    __shared__ uint32_t refsP[CAPREF];
    __shared__ uint32_t refsQ[CAPREF];
    __shared__ u64 s_merge[4 * KTOP];
    __shared__ float s_f[8];
    __shared__ uint32_t s_c[4];
    __shared__ uint16_t topP[KTOP];
    __shared__ uint16_t topQ[KTOP];
    __shared__ uint16_t s_union[2 * KTOP];
    __shared__ int s_nu;

    const int row = blockIdx.x;
    const int tid = threadIdx.x;
    const float* prow = p + (size_t)row * (size_t)V;
    const float* qrow = q + (size_t)row * (size_t)V;

    // ---- sample phase: max of first 2048 elems of each (L2-warm for main pass)
    int smp = V < 2048 ? V : 2048;
    float msP = 0.f, msQ = 0.f;
    for (int i = tid; i < smp; i += NTHREADS) {
        msP = fmaxf(msP, prow[i]);
        msQ = fmaxf(msQ, qrow[i]);
    }
    float MsP = block_max(msP, s_f, tid);
    float MsQ = block_max(msQ, s_f, tid);

    float eps0 = fminf(128.f / (float)V + 1.f / (float)smp, 0.5f);
    float tP = MsP * (1.f - eps0);
    float tQ = MsQ * (1.f - eps0);

    // ---- fused streaming pass: 4 float4 from P + 4 from Q per iteration ----
    int misP = (int)(((uintptr_t)prow >> 2) & 3);
    int misQ = (int)(((uintptr_t)qrow >> 2) & 3);
    int headP = (4 - misP) & 3; if (headP > V) headP = V;
    int headQ = (4 - misQ) & 3; if (headQ > V) headQ = V;

    int ncP = -1, ncQ = -1;   // -1 => needs direct fallback
    if (headP == headQ) {
        int head = headP;
        if (tid == 0) { s_c[0] = 0; s_c[1] = 0; s_c[2] = 0; s_c[3] = 0; }
        __syncthreads();
        int nvec = (V - head) >> 2;
        const float4* vp = reinterpret_cast<const float4*>(prow + head);
        const float4* vq = reinterpret_cast<const float4*>(qrow + head);
        const int per = 4 * NTHREADS;
        int ngrp = nvec / per;

        if (tid < head) {
            push_cand(candP, &s_c[C_CNTP], prow[tid], tid, tP);
            push_cand(candQ, &s_c[C_CNTQ], qrow[tid], tid, tQ);
        }
        #pragma unroll 2
        for (int g = 0; g < ngrp; ++g) {
            int o = g * per + tid;
            float4 a0 = vp[o];
            float4 a1 = vp[o + NTHREADS];
            float4 a2 = vp[o + 2 * NTHREADS];
            float4 a3 = vp[o + 3 * NTHREADS];
            float4 b0 = vq[o];
            float4 b1 = vq[o + NTHREADS];
            float4 b2 = vq[o + 2 * NTHREADS];
            float4 b3 = vq[o + 3 * NTHREADS];
            float mp = max16(a0, a1, a2, a3);
            float mq = max16(b0, b1, b2, b3);
            if (mp >= tP) {
                uint32_t rp = atomicAdd(&s_c[C_REFP], 1u);
                if (rp < CAPREF) refsP[rp] = (uint32_t)o;
            }
            if (mq >= tQ) {
                uint32_t rq = atomicAdd(&s_c[C_REFQ], 1u);
                if (rq < CAPREF) refsQ[rq] = (uint32_t)o;
            }
        }
        // tails: direct per-element push
        for (int i = ngrp * per + tid; i < nvec; i += NTHREADS) {
            float4 a = vp[i], b = vq[i];
            int e = head + (i << 2);
            push_cand(candP, &s_c[C_CNTP], a.x, e, tP);     push_cand(candP, &s_c[C_CNTP], a.y, e + 1, tP);
            push_cand(candP, &s_c[C_CNTP], a.z, e + 2, tP); push_cand(candP, &s_c[C_CNTP], a.w, e + 3, tP);
            push_cand(candQ, &s_c[C_CNTQ], b.x, e, tQ);     push_cand(candQ, &s_c[C_CNTQ], b.y, e + 1, tQ);
            push_cand(candQ, &s_c[C_CNTQ], b.z, e + 2, tQ); push_cand(candQ, &s_c[C_CNTQ], b.w, e + 3, tQ);
        }
        for (int i = head + (nvec << 2) + tid; i < V; i += NTHREADS) {
            push_cand(candP, &s_c[C_CNTP], prow[i], i, tP);
            push_cand(candQ, &s_c[C_CNTQ], qrow[i], i, tQ);
        }
        __syncthreads();
        uint32_t nrefP = s_c[C_REFP], nrefQ = s_c[C_REFQ];
        // expansion: re-read hit groups (L2-warm), per-element push
        if (nrefP <= CAPREF) {
            int units = (int)nrefP * 4;
            for (int u = tid; u < units; u += NTHREADS) {
                int f4 = (int)refsP[u >> 2] + (u & 3) * NTHREADS;
                float4 v = vp[f4];
                int e = head + (f4 << 2);
                push_cand(candP, &s_c[C_CNTP], v.x, e, tP);     push_cand(candP, &s_c[C_CNTP], v.y, e + 1, tP);
                push_cand(candP, &s_c[C_CNTP], v.z, e + 2, tP); push_cand(candP, &s_c[C_CNTP], v.w, e + 3, tP);
            }
        }
        if (nrefQ <= CAPREF) {
            int units = (int)nrefQ * 4;
            for (int u = tid; u < units; u += NTHREADS) {
                int f4 = (int)refsQ[u >> 2] + (u & 3) * NTHREADS;
                float4 v = vq[f4];
                int e = head + (f4 << 2);
                push_cand(candQ, &s_c[C_CNTQ], v.x, e, tQ);     push_cand(candQ, &s_c[C_CNTQ], v.y, e + 1, tQ);
                push_cand(candQ, &s_c[C_CNTQ], v.z, e + 2, tQ); push_cand(candQ, &s_c[C_CNTQ], v.w, e + 3, tQ);
            }
        }
        __syncthreads();
        ncP = (nrefP <= CAPREF) ? (int)s_c[C_CNTP] : -1;
        ncQ = (nrefQ <= CAPREF) ? (int)s_c[C_CNTQ] : -1;
        __syncthreads();
    }

    // ---- fallback / retry (validated cold path; never taken on sane data) ----
    {
        float eps = eps0;
        if (ncP < 0) ncP = collect_direct(prow, V, MsP * (1.f - eps), candP, &s_c[C_CNTP], tid);
        for (int a = 0; a < 10 && (ncP < KTOP || ncP > CAP); ++a) {
            eps = (ncP > CAP) ? eps * 0.25f : fminf(eps * 4.f, 1.f);
            ncP = collect_direct(prow, V, MsP * (1.f - eps), candP, &s_c[C_CNTP], tid);
        }
        if (ncP > CAP) ncP = CAP;
    }
    {
        float eps = eps0;
        if (ncQ < 0) ncQ = collect_direct(qrow, V, MsQ * (1.f - eps), candQ, &s_c[C_CNTQ], tid);
        for (int a = 0; a < 10 && (ncQ < KTOP || ncQ > CAP); ++a) {
            eps = (ncQ > CAP) ? eps * 0.25f : fminf(eps * 4.f, 1.f);
            ncQ = collect_direct(qrow, V, MsQ * (1.f - eps), candQ, &s_c[C_CNTQ], tid);
        }
        if (ncQ > CAP) ncQ = CAP;
    }

    // ---- exact top-50 of each (value desc, index asc — matches jax.lax.top_k)
    find_topk(candP, ncP, topP, s_merge, tid);
    find_topk(candQ, ncQ, topQ, s_merge, tid);

    // ---- union of index sets (wave 0) ----
    if (tid < KTOP) s_union[tid] = topP[tid];
    __syncthreads();
    if (tid < 64) {
        bool fresh = false; uint16_t qi = 0;
        if (tid < KTOP) {
            qi = topQ[tid]; fresh = true;
            for (int j = 0; j < KTOP; ++j) if (topP[j] == qi) fresh = false;
        }
        unsigned long long mb = __ballot(fresh);
        int pos = __popcll(mb & ((1ull << tid) - 1ull));
        if (fresh) s_union[KTOP + pos] = qi;
        if (tid == 0) s_nu = KTOP + __popcll(mb);
    }
    __syncthreads();
    int nu = s_nu;

    // ---- gather union values ----
    float pv = 0.f, qv = 0.f;
    if (tid < nu) {
        int ui = s_union[tid];
        pv = prow[ui];
        qv = qrow[ui];
    }

    // ---- block-reduce masked sums ----
    float sp = pv, sq = qv;
    for (int off = 32; off; off >>= 1) { sp += __shfl_down(sp, off); sq += __shfl_down(sq, off); }
    int wid = tid >> 6;
    if ((tid & 63) == 0) { s_f[wid] = sp; s_f[4 + wid] = sq; }
    __syncthreads();
    if (tid == 0) {
        float a = 0.f, b = 0.f;
        for (int w = 0; w < NTHREADS / 64; ++w) { a += s_f[w]; b += s_f[4 + w]; }
        s_f[0] = a; s_f[4] = b;
    }
    __syncthreads();
    float sump = s_f[0], sumq = s_f[4];
    __syncthreads();

    // ---- JSD over union (identical formula to validated kernels) ----
    float term = 0.f;
    if (tid < nu) {
        float pn = pv / (sump + EPSV);
        float qn = qv / (sumq + EPSV);
        float mn = 0.5f * (pn + qn);
        float ps = pn + EPSV, qs = qn + EPSV, ms = mn + EPSV;
        term = 0.5f * (ps * logf(ps / ms) + qs * logf(qs / ms));
    }
    for (int off = 32; off; off >>= 1) term += __shfl_down(term, off);
    if ((tid & 63) == 0) s_f[wid] = term;
    __syncthreads();
    if (tid == 0) {
        float a = 0.f;
        for (int w = 0; w < NTHREADS / 64; ++w) a += s_f[w];
        out[row] = a;
    }
}

extern "C" void kernel_launch(void* const* d_in, const int* in_sizes, int n_in,
                              void* d_out, int out_size, void* d_ws, size_t ws_size,
                              hipStream_t stream) {
    const float* p = (const float*)d_in[0];
    const float* q = (const float*)d_in[1];
    float* out = (float*)d_out;
    if (out_size <= 0) return;
    int N = out_size;            // B*S rows
    int V = in_sizes[0] / N;     // vocab size
    topk_jsd_kernel<<<dim3(N), dim3(NTHREADS), 0, stream>>>(p, q, out, V);
}